// Round 13
// baseline (4386.568 us; speedup 1.0000x reference)
//
#include <hip/hip_runtime.h>
#include <math.h>

// ---------------------------------------------------------------------------
// SRRNN: state-regularized GRU.  B=64, S=512, I=256, H=512, K=256, TEMP=1.
//
// Round 13: MALL-side reduction via monotonic counting atomicAdd.
//  - One u64 accumulator per (g,b,k): each CU atomicAdds
//    (1<<50) | (partial * 2^24). Bits 50-63: contribution count (16/step,
//    monotone over all 512 steps: 8192 < 2^14). Bits 0-49: fixed-point sum
//    (total < 2^44 -> never carries into the count).
//  - Consumer polls ONE word per (b,k) until count == 16*(t+1); then
//    d_t = (w - prev) * 2^-24, prev kept in registers. Monotonic counter
//    => no slots, no zeroing, no ABA. memset(0) per launch.
//  - Poll volume 64KB -> 8KB per CU per step (16 MB -> 2 MB chip-wide);
//    16-way unpack+sum VALU reduce eliminated (the MALL does the sum).
//  - Compute path (register weights, chunked LDS, gi shadow, softmax,
//    gh/h_new) = R12 verbatim.
// ---------------------------------------------------------------------------

#define B_ 64
#define S_ 512
#define I_ 256
#define H_ 512
#define K_ 256
#define G3H 1536
#define NGRP 16
#define GCU 16
#define NB 4
#define DPC 32     // dims per CU
#define TPB 512
#define SPIN_MAX (1 << 15)

#define CNT_SHIFT 50
#define SUM_MASK ((1ull << 50) - 1)
#define FIX_SCALE 16777216.0f          // 2^24
#define INV_FIX 5.9604644775390625e-8f // 2^-24

// workspace layout (bytes)
#define WS_SWT 4096
#define WS_SWT_SZ (G3H * K_ * 4)                       // 1572864
#define WS_GH0 (WS_SWT + WS_SWT_SZ)
#define WS_GH0_SZ (B_ * G3H * 4)                       // 393216
#define WS_ACC (WS_GH0 + WS_GH0_SZ)                    // 1970176 (8B aligned)
#define WS_ACC_SZ (NGRP * NB * K_ * 8)                 // 131072

// LDS float offsets (R10/R11/R12 map)
#define L_ST 0               // s_T[32][256]   j-major
#define L_SSL 8192           // s_sl[256][36]  k-major
#define L_XCH 17408          // x_ch [4][16][20]
#define L_PCH 18688          // p_ch [4][16][20]
#define L_GI 19968           // gi_sl [4][96]
#define L_GH 20352           // gh_sl [4][96]
#define L_HC 20736           // hc_sl [4][32]
#define L_HP 20864           // hp_sl [4][32]
#define L_BIH 20992          // [96]
#define L_BHH 21088          // [96]
#define L_D 21184            // d_sl [4][256]
#define SMEM_BYTES 90112     // >80KB -> 1 block/CU

#define OUT_OFF_HN (B_ * S_ * H_)
#define OUT_OFF_P (OUT_OFF_HN + B_ * H_)

#define AGENT __HIP_MEMORY_SCOPE_AGENT
#define RLX __ATOMIC_RELAXED

// ---------------------------------------------------------------------------
__global__ void kernel_swt(const float* __restrict__ Whh,
                           const float* __restrict__ states,
                           float* __restrict__ SWT) {
  int r0 = blockIdx.x * 8;
  int k = threadIdx.x;  // 0..255
  const float* sr = states + (size_t)k * H_;
  float acc[8];
#pragma unroll
  for (int q = 0; q < 8; ++q) acc[q] = 0.f;
  for (int j = 0; j < H_; ++j) {
    float sv = sr[j];
#pragma unroll
    for (int q = 0; q < 8; ++q) acc[q] += Whh[(size_t)(r0 + q) * H_ + j] * sv;
  }
#pragma unroll
  for (int q = 0; q < 8; ++q) SWT[(size_t)(r0 + q) * K_ + k] = acc[q];
}

__global__ void kernel_gh0(const float* __restrict__ Whh,
                           const float* __restrict__ h0,
                           float* __restrict__ Gh0) {
  int b = blockIdx.x;
  int tid = threadIdx.x;  // 256
  __shared__ float h[H_];
  for (int e = tid; e < H_; e += 256) h[e] = h0[(size_t)b * H_ + e];
  __syncthreads();
  for (int r = tid; r < G3H; r += 256) {
    const float* wr = Whh + (size_t)r * H_;
    float acc = 0.f;
    for (int j = 0; j < H_; ++j) acc += wr[j] * h[j];
    Gh0[(size_t)b * G3H + r] = acc;
  }
}

// ---------------------------------------------------------------------------
__device__ __forceinline__ float dot4(float4 a, float4 b) {
  return a.x * b.x + a.y * b.y + a.z * b.z + a.w * b.w;
}
__device__ __forceinline__ unsigned long long tload(
    const unsigned long long* p) {
  return __hip_atomic_load(p, RLX, AGENT);
}
__device__ __forceinline__ void tadd(unsigned long long* p, float v) {
  unsigned long long w =
      (1ull << CNT_SHIFT) | (unsigned long long)(v * FIX_SCALE);
  (void)__hip_atomic_fetch_add(p, w, RLX, AGENT);
}

__global__ __launch_bounds__(TPB, 2) void srrnn_main(
    const float* __restrict__ input, const float* __restrict__ h0,
    const float* __restrict__ W_ih, const float* __restrict__ bias_ih,
    const float* __restrict__ bias_hh, const float* __restrict__ states,
    const float* __restrict__ SWT, const float* __restrict__ Gh0,
    unsigned long long* __restrict__ acc_g,
    float* __restrict__ out, float* __restrict__ hn,
    float* __restrict__ probs) {
  const int tid = threadIdx.x;
  const int g = blockIdx.x >> 4;   // group 0..15
  const int cu = blockIdx.x & 15;  // CU in group
  const int d0 = cu << 5;          // owned dim base (32 dims)

  extern __shared__ float smem[];
  float* s_T = smem + L_ST;        // [j][256]
  float* s_sl = smem + L_SSL;      // [k][36]
  float* x_ch = smem + L_XCH;      // [4][16][20]
  float* p_ch = smem + L_PCH;      // [4][16][20]
  float* gi_sl = smem + L_GI;
  float* gh_sl = smem + L_GH;
  float* hc_sl = smem + L_HC;
  float* hp_sl = smem + L_HP;
  float* bih_sl = smem + L_BIH;
  float* bhh_sl = smem + L_BHH;
  float* d_sl = smem + L_D;

  const int wv = tid >> 6, lane = tid & 63;
  const int rowblk = tid >> 4, kseg = tid & 15;  // GEMM org: 32 rowblk x 16 kseg

  // ---- setup ----
  for (int e = tid; e < K_ * DPC; e += TPB) {
    int k = e >> 5, j = e & 31;
    float v = states[((size_t)k << 9) + d0 + j];
    s_T[j * 256 + k] = v;
    s_sl[k * 36 + j] = v;
  }
  if (tid < 96) {
    int grow = ((tid >> 5) << 9) + d0 + (tid & 31);
    bih_sl[tid] = bias_ih[grow];
    bhh_sl[tid] = bias_hh[grow];
  }
  if (tid < 128) {
    int b = tid >> 5, j = tid & 31;
    hp_sl[(b << 5) + j] = h0[((size_t)(g * NB + b) << 9) + d0 + j];
  }
  if (tid < 384) {
    int b = tid / 96, r = tid % 96;
    int grow = ((r >> 5) << 9) + d0 + (r & 31);
    gh_sl[b * 96 + r] = Gh0[(size_t)(g * NB + b) * G3H + grow];
  }
  // weight fragments -> registers: 3 rows x 16 k per thread, both matrices
  float4 wi[3][4], wh[3][4];
#pragma unroll
  for (int i = 0; i < 3; ++i) {
    int r = rowblk * 3 + i;  // 0..95
    int grow = ((r >> 5) << 9) + d0 + (r & 31);
    const float4* si = (const float4*)(W_ih + (size_t)grow * K_ + (kseg << 4));
    const float4* sh = (const float4*)(SWT + (size_t)grow * K_ + (kseg << 4));
    wi[i][0] = si[0]; wi[i][1] = si[1]; wi[i][2] = si[2]; wi[i][3] = si[3];
    wh[i][0] = sh[0]; wh[i][1] = sh[1]; wh[i][2] = sh[2]; wh[i][3] = sh[3];
  }
  __syncthreads();

  // ---- pre-loop: stage x(0) chunked, gi(0) ----
  if (tid < 256) {
    int b = tid >> 6, c = tid & 63;
    float4 v = *((const float4*)(input + ((size_t)(g * NB + b) * S_) * I_) + c);
    *(float4*)(x_ch + (b * 16 + (c >> 2)) * 20 + ((c & 3) << 2)) = v;
  }
  __syncthreads();
  {
    float acc[4][3] = {};
#pragma unroll
    for (int b = 0; b < 4; ++b) {
      const float4* xp = (const float4*)(x_ch + (b * 16 + kseg) * 20);
#pragma unroll
      for (int c = 0; c < 4; ++c) {
        float4 xv = xp[c];
#pragma unroll
        for (int i = 0; i < 3; ++i) acc[b][i] += dot4(wi[i][c], xv);
      }
    }
#pragma unroll
    for (int b = 0; b < 4; ++b)
#pragma unroll
      for (int i = 0; i < 3; ++i) {
        float v = acc[b][i];
        v += __shfl_xor(v, 1); v += __shfl_xor(v, 2);
        v += __shfl_xor(v, 4); v += __shfl_xor(v, 8);
        acc[b][i] = v;
      }
    if (kseg == 0) {
#pragma unroll
      for (int b = 0; b < 4; ++b)
#pragma unroll
        for (int i = 0; i < 3; ++i) gi_sl[b * 96 + rowblk * 3 + i] = acc[b][i];
    }
  }
  __syncthreads();

  // per-thread previous accumulator snapshots (monotonic protocol)
  unsigned long long pv0 = 0ull, pv1 = 0ull;
  const int p_bp = tid >> 8;       // 0..1
  const int p_k = tid & 255;
  unsigned long long* a0 = acc_g + (((size_t)(g * NB + p_bp)) << 8) + p_k;
  unsigned long long* a1 = acc_g + (((size_t)(g * NB + p_bp + 2)) << 8) + p_k;

  for (int t = 0; t < S_; ++t) {
    // ---- A: gates + h_cand over owned 32 dims ----
    if (tid < 128) {
      int b = tid >> 5, j = tid & 31;
      float gir = gi_sl[b * 96 + j] + bih_sl[j];
      float giz = gi_sl[b * 96 + 32 + j] + bih_sl[32 + j];
      float gin = gi_sl[b * 96 + 64 + j] + bih_sl[64 + j];
      float ghr = gh_sl[b * 96 + j] + bhh_sl[j];
      float ghz = gh_sl[b * 96 + 32 + j] + bhh_sl[32 + j];
      float ghn = gh_sl[b * 96 + 64 + j] + bhh_sl[64 + j];
      float r = 1.f / (1.f + expf(-(gir + ghr)));
      float z = 1.f / (1.f + expf(-(giz + ghz)));
      float n = tanhf(gin + r * ghn);
      hc_sl[(b << 5) + j] = (1.f - z) * n + z * hp_sl[(b << 5) + j];
    }
    __syncthreads();

    // ---- B: dist partials (vectorized) -> counting atomicAdds ----
    {
      int b = tid >> 7;              // 0..3
      int sub = tid & 127;
      int k4 = sub >> 1;             // float4-of-k index 0..63
      int jh = sub & 1;              // j-half
      const float* hb = hc_sl + (b << 5) + (jh << 4);
      const float4* sp = (const float4*)(s_T + ((jh << 4) * 256) + (k4 << 2));
      float ax = 0.f, ay = 0.f, az = 0.f, aw = 0.f;
#pragma unroll
      for (int jj = 0; jj < 16; ++jj) {
        float4 s4 = sp[jj * 64];
        float hv = hb[jj];
        float e;
        e = hv - s4.x; ax += e * e;
        e = hv - s4.y; ay += e * e;
        e = hv - s4.z; az += e * e;
        e = hv - s4.w; aw += e * e;
      }
      ax += __shfl_xor(ax, 1);       // both jh-halves now hold full sums
      ay += __shfl_xor(ay, 1);
      az += __shfl_xor(az, 1);
      aw += __shfl_xor(aw, 1);
      unsigned long long* dst =
          acc_g + (((size_t)(g * NB + b)) << 8) + (k4 << 2);
      if (jh == 0) {
        tadd(dst + 0, ax);
        tadd(dst + 1, ay);
      } else {
        tadd(dst + 2, az);
        tadd(dst + 3, aw);
      }
    }

    // ---- C (shadow): stage x(t+1) + gi(t+1) GEMM (register W_ih) ----
    if (t + 1 < S_) {
      if (tid < 256) {
        int b = tid >> 6, c = tid & 63;
        float4 v = *((const float4*)(input +
                     ((size_t)(g * NB + b) * S_ + (t + 1)) * I_) + c);
        *(float4*)(x_ch + (b * 16 + (c >> 2)) * 20 + ((c & 3) << 2)) = v;
      }
      __syncthreads();
      {
        float acc[4][3] = {};
#pragma unroll
        for (int b = 0; b < 4; ++b) {
          const float4* xp = (const float4*)(x_ch + (b * 16 + kseg) * 20);
#pragma unroll
          for (int c = 0; c < 4; ++c) {
            float4 xv = xp[c];
#pragma unroll
            for (int i = 0; i < 3; ++i) acc[b][i] += dot4(wi[i][c], xv);
          }
        }
#pragma unroll
        for (int b = 0; b < 4; ++b)
#pragma unroll
          for (int i = 0; i < 3; ++i) {
            float v = acc[b][i];
            v += __shfl_xor(v, 1); v += __shfl_xor(v, 2);
            v += __shfl_xor(v, 4); v += __shfl_xor(v, 8);
            acc[b][i] = v;
          }
        if (kseg == 0) {
#pragma unroll
          for (int b = 0; b < 4; ++b)
#pragma unroll
            for (int i = 0; i < 3; ++i)
              gi_sl[b * 96 + rowblk * 3 + i] = acc[b][i];
        }
      }
    }

    // ---- P: poll counters (1 word per (b,k)), delta -> d_sl ----
    {
      const unsigned cnt = 16u * (unsigned)(t + 1);
      unsigned long long w0 = tload(a0);
      unsigned long long w1 = tload(a1);
      int it = 0;
      while ((unsigned)(w0 >> CNT_SHIFT) != cnt && ++it < SPIN_MAX)
        w0 = tload(a0);
      it = 0;
      while ((unsigned)(w1 >> CNT_SHIFT) != cnt && ++it < SPIN_MAX)
        w1 = tload(a1);
      d_sl[(p_bp << 8) + p_k] =
          (float)((w0 - pv0) & SUM_MASK) * INV_FIX;
      d_sl[((p_bp + 2) << 8) + p_k] =
          (float)((w1 - pv1) & SUM_MASK) * INV_FIX;
      pv0 = w0;
      pv1 = w1;
    }
    __syncthreads();

    // ---- G: softmax (waves 0-3, wave = batch) -> p_ch chunked + probs ----
    if (wv < NB) {
      int b = wv;
      const float* db = d_sl + (b << 8);
      float dd0 = db[lane], dd1 = db[lane + 64], dd2 = db[lane + 128],
            dd3 = db[lane + 192];
      float mn = fminf(fminf(dd0, dd1), fminf(dd2, dd3));
#pragma unroll
      for (int off = 32; off >= 1; off >>= 1) mn = fminf(mn, __shfl_xor(mn, off));
      float e0 = expf(mn - dd0), e1 = expf(mn - dd1), e2 = expf(mn - dd2),
            e3 = expf(mn - dd3);
      float s = (e0 + e1) + (e2 + e3);
#pragma unroll
      for (int off = 32; off >= 1; off >>= 1) s += __shfl_xor(s, off);
      float inv = 1.f / s;
      e0 *= inv; e1 *= inv; e2 *= inv; e3 *= inv;
      int hi = lane >> 4, lo = lane & 15;
      p_ch[(b * 16 + hi + 0) * 20 + lo] = e0;
      p_ch[(b * 16 + hi + 4) * 20 + lo] = e1;
      p_ch[(b * 16 + hi + 8) * 20 + lo] = e2;
      p_ch[(b * 16 + hi + 12) * 20 + lo] = e3;
      if (cu == 0) {
        float* pr = probs + (((size_t)(g * NB + b) * S_ + t) << 8);
        pr[lane] = e0; pr[lane + 64] = e1; pr[lane + 128] = e2;
        pr[lane + 192] = e3;
      }
    }
    __syncthreads();

    // ---- H1: gh(t+1) = p @ SWT^T from registers; p from chunked layout ----
    if (t + 1 < S_) {
      float acc[4][3] = {};
#pragma unroll
      for (int b = 0; b < 4; ++b) {
        const float4* xp = (const float4*)(p_ch + (b * 16 + kseg) * 20);
#pragma unroll
        for (int c = 0; c < 4; ++c) {
          float4 xv = xp[c];
#pragma unroll
          for (int i = 0; i < 3; ++i) acc[b][i] += dot4(wh[i][c], xv);
        }
      }
#pragma unroll
      for (int b = 0; b < 4; ++b)
#pragma unroll
        for (int i = 0; i < 3; ++i) {
          float v = acc[b][i];
          v += __shfl_xor(v, 1); v += __shfl_xor(v, 2);
          v += __shfl_xor(v, 4); v += __shfl_xor(v, 8);
          acc[b][i] = v;
        }
      if (kseg == 0) {
#pragma unroll
        for (int b = 0; b < 4; ++b)
#pragma unroll
          for (int i = 0; i < 3; ++i)
            gh_sl[b * 96 + rowblk * 3 + i] = acc[b][i];
      }
    }

    // ---- H2: h_new. thread = (b, j, kq) ----
    {
      int b = tid >> 7, j = (tid >> 2) & 31, kq = tid & 3;
      float a = 0.f;
#pragma unroll
      for (int i = 0; i < 16; ++i) {
        float4 p4 = *(const float4*)(p_ch + (b * 16 + i) * 20 + (kq << 2));
        int k = (i << 4) + (kq << 2);
        a += p4.x * s_sl[(k + 0) * 36 + j] + p4.y * s_sl[(k + 1) * 36 + j] +
             p4.z * s_sl[(k + 2) * 36 + j] + p4.w * s_sl[(k + 3) * 36 + j];
      }
      a += __shfl_xor(a, 1);
      a += __shfl_xor(a, 2);
      if (kq == 0) {
        hp_sl[(b << 5) + j] = a;
        out[(((size_t)(g * NB + b) * S_ + t) << 9) + d0 + j] = a;
      }
    }
    __syncthreads();
  }

  // ---- final hidden state ----
  if (tid < 128) {
    int b = tid >> 5, j = tid & 31;
    hn[((size_t)(g * NB + b) << 9) + d0 + j] = hp_sl[(b << 5) + j];
  }
}

// ---------------------------------------------------------------------------
extern "C" void kernel_launch(void* const* d_in, const int* in_sizes, int n_in,
                              void* d_out, int out_size, void* d_ws,
                              size_t ws_size, hipStream_t stream) {
  const float* input = (const float*)d_in[0];
  const float* h0 = (const float*)d_in[1];
  const float* W_ih = (const float*)d_in[2];
  const float* W_hh = (const float*)d_in[3];
  const float* bias_ih = (const float*)d_in[4];
  const float* bias_hh = (const float*)d_in[5];
  const float* states = (const float*)d_in[6];
  float* out = (float*)d_out;

  char* ws = (char*)d_ws;
  float* SWT = (float*)(ws + WS_SWT);
  float* Gh0 = (float*)(ws + WS_GH0);
  unsigned long long* acc_g = (unsigned long long*)(ws + WS_ACC);

  // zero the monotonic accumulators each launch (count 0, sum 0)
  (void)hipMemsetAsync(ws + WS_ACC, 0, WS_ACC_SZ, stream);
  kernel_swt<<<G3H / 8, 256, 0, stream>>>(W_hh, states, SWT);
  kernel_gh0<<<B_, 256, 0, stream>>>(W_hh, h0, Gh0);

  (void)hipFuncSetAttribute(reinterpret_cast<const void*>(srrnn_main),
                            hipFuncAttributeMaxDynamicSharedMemorySize,
                            SMEM_BYTES);
  srrnn_main<<<NGRP * GCU, TPB, SMEM_BYTES, stream>>>(
      input, h0, W_ih, bias_ih, bias_hh, states, SWT, Gh0, acc_g,
      out, out + OUT_OFF_HN, out + OUT_OFF_P);
}